// Round 1
// 694.881 us; speedup vs baseline: 1.0616x; 1.0616x over previous
//
#include <hip/hip_runtime.h>

// Problem constants (fixed by reference)
#define N_B   8
#define C_CH  512
#define CT_T  256
#define L_T   64
#define HEADS 8
#define D_H   64
#define HW_PX 16384   // 128*128

typedef short    bf16x8 __attribute__((ext_vector_type(8)));
typedef float    f32x16 __attribute__((ext_vector_type(16)));
typedef unsigned u32x4  __attribute__((ext_vector_type(4)));

__device__ __forceinline__ unsigned pk_bf16(float lo, float hi) {
    unsigned r;
    asm("v_cvt_pk_bf16_f32 %0, %1, %2" : "=v"(r) : "v"(lo), "v"(hi));
    return r;
}
__device__ __forceinline__ float lo_f(unsigned w) { return __uint_as_float(w << 16); }
__device__ __forceinline__ float hi_f(unsigned w) { return __uint_as_float(w & 0xFFFF0000u); }

// Split 8 k-contiguous f32 into hi/lo bf16 packed fragments (bf16x3 precision trick):
// x = hi + lo with |err| ~ 2^-17 relative.
__device__ __forceinline__ void split8(const float x[8], u32x4& h, u32x4& l) {
#pragma unroll
    for (int j = 0; j < 4; ++j) {
        float a = x[2 * j], b = x[2 * j + 1];
        unsigned ph = pk_bf16(a, b);
        h[j] = ph;
        l[j] = pk_bf16(a - lo_f(ph), b - hi_f(ph));
    }
}

__device__ __forceinline__ f32x16 mfma_bf16(u32x4 a, u32x4 b, f32x16 c) {
    return __builtin_amdgcn_mfma_f32_32x32x16_bf16(
        __builtin_bit_cast(bf16x8, a), __builtin_bit_cast(bf16x8, b), c, 0, 0, 0);
}

// ---------------------------------------------------------------------------
// Kernel A (unchanged): v = Wv@token + bv, k = (Wk@token + bk) * (log2e/8).
// Scale folded into k so attention uses exp2 directly.
// ---------------------------------------------------------------------------
__global__ __launch_bounds__(256) void proj_kernel(
    const float* __restrict__ token,
    const float* __restrict__ Wv, const float* __restrict__ bv,
    const float* __restrict__ Wk, const float* __restrict__ bk,
    float* __restrict__ vw, float* __restrict__ kw)
{
    int t = blockIdx.x * 256 + threadIdx.x;      // 8*512*64 = 262144 threads
    int l = t & (L_T - 1);
    int c = (t >> 6) & (C_CH - 1);
    int n = t >> 15;

    const float* tok = token + (size_t)n * CT_T * L_T + l;
    const float* wv  = Wv + (size_t)c * CT_T;
    const float* wk  = Wk + (size_t)c * CT_T;

    float av = 0.f, ak = 0.f;
#pragma unroll 8
    for (int ct = 0; ct < CT_T; ++ct) {
        float tv = tok[ct * L_T];
        av = fmaf(wv[ct], tv, av);
        ak = fmaf(wk[ct], tv, ak);
    }
    av += bv[c];
    ak += bk[c];
    const float kscale = 0.125f * 1.44269504088896340736f; // (1/sqrt(64)) * log2(e)
    vw[t] = av;
    kw[t] = ak * kscale;
}

// ---------------------------------------------------------------------------
// Kernel B: MFMA flash-attention (exact softmax, L=64 fits in registers).
//
// One wave (64 lanes) owns one (n,h) and 8 consecutive 32-px tiles.
// Per tile:
//   S^T(64l x 32px) = mfma(A=K^T, B=Q)   [swapped operands: px is lane-local col]
//   softmax over l: 32 in-reg values + 1 shfl_xor(32) with partner half
//   O^T(64d x 32px) = mfma(A=V, B=P^T)   [P redistributed via cvt_pk+permlane32_swap]
// All MFMA inputs use bf16 hi/lo split, 3-term products => fp32-equivalent accuracy.
//
// Layouts (32x32x16_bf16, verified in docs):
//   A: row=lane&31, k=8*(lane>>5)+i   B: col=lane&31, k=8*(lane>>5)+i
//   C/D: col=lane&31, row=(reg&3)+8*(reg>>2)+4*(lane>>5)
// P->B mapping (derived from C/D formula): for K=16 slot s, tile t=s>>1,
// base=8*(s&1): B word j pairs = regs {base+2j,base+2j+1} from BOTH lane halves;
// permlane32_swap(x=pk(base+0..3), y=pk(base+4..7)) yields r[0]=low-half words,
// r[1]=high-half words for all lanes.
// ---------------------------------------------------------------------------
__global__ __launch_bounds__(64, 2) void attn_kernel(
    const float* __restrict__ feature,
    const float* __restrict__ vw, const float* __restrict__ kw,
    float* __restrict__ out)
{
    const int lane = threadIdx.x;    // 0..63
    const int c    = lane & 31;      // output/px column within tile
    const int hi   = lane >> 5;      // lane half

    const int bid = blockIdx.x;      // 4096 = 64 px-groups * 64 (n,h)
    const int nh  = bid & 63;        // n*8 + h
    const int grp = bid >> 6;        // 256-px group

    const float* Kb = kw + (size_t)nh * (D_H * L_T);   // K[dd][l]
    const float* Vb = vw + (size_t)nh * (D_H * L_T);   // V[dd][l]

    // ---- K as A-fragments of mfma(K^T, Q): frag(t,s): row l = 32t+c, k=d=16s+8hi+i
    u32x4 kh[2][4], kl[2][4];
#pragma unroll
    for (int t = 0; t < 2; ++t)
#pragma unroll
        for (int s = 0; s < 4; ++s) {
            float tmp[8];
#pragma unroll
            for (int i = 0; i < 8; ++i)
                tmp[i] = Kb[(16 * s + 8 * hi + i) * L_T + 32 * t + c];  // K[d][l] -> A[l][d]
            split8(tmp, kh[t][s], kl[t][s]);
        }

    // ---- V as A-fragments of mfma(V, P^T): frag(u,s): row dd = 32u+c, k=l=16s+8hi+i
    u32x4 vh[2][4], vl[2][4];
#pragma unroll
    for (int u = 0; u < 2; ++u)
#pragma unroll
        for (int s = 0; s < 4; ++s) {
            const float* p = Vb + (size_t)(32 * u + c) * L_T + 16 * s + 8 * hi; // 32B-aligned
            float4 q0 = *(const float4*)(p);
            float4 q1 = *(const float4*)(p + 4);
            float tmp[8] = {q0.x, q0.y, q0.z, q0.w, q1.x, q1.y, q1.z, q1.w};
            split8(tmp, vh[u][s], vl[u][s]);
        }

    const size_t fb = (size_t)nh * D_H * HW_PX;
    const int px_base = grp * 256 + c;

#pragma unroll 1
    for (int it = 0; it < 8; ++it) {
        const int px = px_base + it * 32;

        // ---- QK^T: S^T[l][px], l = 32t + (r&3)+8*(r>>2)+4*hi, px = tile+c
        f32x16 accS[2];
#pragma unroll
        for (int r = 0; r < 16; ++r) { accS[0][r] = 0.f; accS[1][r] = 0.f; }

#pragma unroll
        for (int s = 0; s < 4; ++s) {
            float q[8];
#pragma unroll
            for (int i = 0; i < 8; ++i)        // Q[d][px]: 128B-coalesced per half-wave
                q[i] = feature[fb + (size_t)(16 * s + 8 * hi + i) * HW_PX + px];
            u32x4 qh, ql;
            split8(q, qh, ql);
#pragma unroll
            for (int t = 0; t < 2; ++t) {
                accS[t] = mfma_bf16(kh[t][s], qh, accS[t]);
                accS[t] = mfma_bf16(kh[t][s], ql, accS[t]);
                accS[t] = mfma_bf16(kl[t][s], qh, accS[t]);
            }
        }

        // ---- softmax over l (base-2 domain; scale already folded into kw)
        float m = accS[0][0];
#pragma unroll
        for (int r = 1; r < 16; ++r) m = fmaxf(m, accS[0][r]);
#pragma unroll
        for (int r = 0; r < 16; ++r) m = fmaxf(m, accS[1][r]);
        m = fmaxf(m, __shfl_xor(m, 32));        // partner half holds other 32 l's, same px
        float sum = 0.f;
#pragma unroll
        for (int t = 0; t < 2; ++t)
#pragma unroll
            for (int r = 0; r < 16; ++r) {
                float e = __builtin_amdgcn_exp2f(accS[t][r] - m);
                accS[t][r] = e;                 // unnormalized P in-place
                sum += e;
            }
        sum += __shfl_xor(sum, 32);
        const float rinv = 1.0f / sum;          // normalization deferred to epilogue

        // ---- PV: O^T[dd][px]
        f32x16 accO[2];
#pragma unroll
        for (int r = 0; r < 16; ++r) { accO[0][r] = 0.f; accO[1][r] = 0.f; }

#pragma unroll
        for (int s = 0; s < 4; ++s) {
            const int t  = s >> 1;
            const int b0 = 8 * (s & 1);
            float e0 = accS[t][b0 + 0], e1 = accS[t][b0 + 1];
            float e2 = accS[t][b0 + 2], e3 = accS[t][b0 + 3];
            float e4 = accS[t][b0 + 4], e5 = accS[t][b0 + 5];
            float e6 = accS[t][b0 + 6], e7 = accS[t][b0 + 7];
            unsigned xh0 = pk_bf16(e0, e1), xh1 = pk_bf16(e2, e3);
            unsigned yh0 = pk_bf16(e4, e5), yh1 = pk_bf16(e6, e7);
            unsigned xl0 = pk_bf16(e0 - lo_f(xh0), e1 - hi_f(xh0));
            unsigned xl1 = pk_bf16(e2 - lo_f(xh1), e3 - hi_f(xh1));
            unsigned yl0 = pk_bf16(e4 - lo_f(yh0), e5 - hi_f(yh0));
            unsigned yl1 = pk_bf16(e6 - lo_f(yh1), e7 - hi_f(yh1));
            // swap(a,b): a <- [a_lo, b_lo], b <- [a_hi, b_hi]
            auto r0 = __builtin_amdgcn_permlane32_swap(xh0, yh0, false, false);
            auto r1 = __builtin_amdgcn_permlane32_swap(xh1, yh1, false, false);
            auto r2 = __builtin_amdgcn_permlane32_swap(xl0, yl0, false, false);
            auto r3 = __builtin_amdgcn_permlane32_swap(xl1, yl1, false, false);
            u32x4 pbh, pbl;
            pbh[0] = r0[0]; pbh[1] = r1[0]; pbh[2] = r0[1]; pbh[3] = r1[1];
            pbl[0] = r2[0]; pbl[1] = r3[0]; pbl[2] = r2[1]; pbl[3] = r3[1];
#pragma unroll
            for (int u = 0; u < 2; ++u) {
                accO[u] = mfma_bf16(vh[u][s], pbh, accO[u]);
                accO[u] = mfma_bf16(vh[u][s], pbl, accO[u]);
                accO[u] = mfma_bf16(vl[u][s], pbh, accO[u]);
            }
        }

        // ---- epilogue: normalize + residual + store (128B-coalesced per half-wave)
#pragma unroll
        for (int u = 0; u < 2; ++u)
#pragma unroll
            for (int r = 0; r < 16; ++r) {
                const int dd = 32 * u + (r & 3) + 8 * (r >> 2) + 4 * hi;
                const size_t a = fb + (size_t)dd * HW_PX + px;
                out[a] = fmaf(accO[u][r], rinv, feature[a]);  // residual re-read: L2 hit
            }
    }
}

// ---------------------------------------------------------------------------
extern "C" void kernel_launch(void* const* d_in, const int* in_sizes, int n_in,
                              void* d_out, int out_size, void* d_ws, size_t ws_size,
                              hipStream_t stream)
{
    const float* feature = (const float*)d_in[0];
    const float* token   = (const float*)d_in[1];
    const float* Wv      = (const float*)d_in[2];
    const float* bv      = (const float*)d_in[3];
    const float* Wk      = (const float*)d_in[4];
    const float* bk      = (const float*)d_in[5];
    float* out = (float*)d_out;

    float* vw = (float*)d_ws;                       // 262144 floats
    float* kw = vw + (size_t)N_B * C_CH * L_T;      // 262144 floats

    proj_kernel<<<(N_B * C_CH * L_T) / 256, 256, 0, stream>>>(token, Wv, bv, Wk, bk, vw, kw);

    // 64 px-groups (256 px each) x 64 (n,h), one wave per block
    attn_kernel<<<64 * 64, 64, 0, stream>>>(feature, vw, kw, out);
}

// Round 2
// 500.072 us; speedup vs baseline: 1.4752x; 1.3896x over previous
//
#include <hip/hip_runtime.h>

// Problem constants (fixed by reference)
#define N_B   8
#define C_CH  512
#define CT_T  256
#define L_T   64
#define HEADS 8
#define D_H   64
#define HW_PX 16384   // 128*128

typedef short    bf16x8 __attribute__((ext_vector_type(8)));
typedef float    f32x16 __attribute__((ext_vector_type(16)));
typedef unsigned u32x4  __attribute__((ext_vector_type(4)));

__device__ __forceinline__ unsigned pk_bf16(float lo, float hi) {
    unsigned r;
    asm("v_cvt_pk_bf16_f32 %0, %1, %2" : "=v"(r) : "v"(lo), "v"(hi));
    return r;
}
__device__ __forceinline__ float lo_f(unsigned w) { return __uint_as_float(w << 16); }
__device__ __forceinline__ float hi_f(unsigned w) { return __uint_as_float(w & 0xFFFF0000u); }

// Split 8 k-contiguous f32 into hi/lo bf16 packed fragments (bf16x3 trick):
// x = hi + lo with |err| ~ 2^-17 relative.
__device__ __forceinline__ void split8(const float x[8], u32x4& h, u32x4& l) {
#pragma unroll
    for (int j = 0; j < 4; ++j) {
        float a = x[2 * j], b = x[2 * j + 1];
        unsigned ph = pk_bf16(a, b);
        h[j] = ph;
        l[j] = pk_bf16(a - lo_f(ph), b - hi_f(ph));
    }
}

__device__ __forceinline__ f32x16 mfma_bf16(u32x4 a, u32x4 b, f32x16 c) {
    return __builtin_amdgcn_mfma_f32_32x32x16_bf16(
        __builtin_bit_cast(bf16x8, a), __builtin_bit_cast(bf16x8, b), c, 0, 0, 0);
}

// ---------------------------------------------------------------------------
// Kernel A (unchanged): v = Wv@token + bv, k = (Wk@token + bk) * (log2e/8).
// ---------------------------------------------------------------------------
__global__ __launch_bounds__(256) void proj_kernel(
    const float* __restrict__ token,
    const float* __restrict__ Wv, const float* __restrict__ bv,
    const float* __restrict__ Wk, const float* __restrict__ bk,
    float* __restrict__ vw, float* __restrict__ kw)
{
    int t = blockIdx.x * 256 + threadIdx.x;      // 8*512*64 = 262144 threads
    int l = t & (L_T - 1);
    int c = (t >> 6) & (C_CH - 1);
    int n = t >> 15;

    const float* tok = token + (size_t)n * CT_T * L_T + l;
    const float* wv  = Wv + (size_t)c * CT_T;
    const float* wk  = Wk + (size_t)c * CT_T;

    float av = 0.f, ak = 0.f;
#pragma unroll 8
    for (int ct = 0; ct < CT_T; ++ct) {
        float tv = tok[ct * L_T];
        av = fmaf(wv[ct], tv, av);
        ak = fmaf(wk[ct], tv, ak);
    }
    av += bv[c];
    ak += bk[c];
    const float kscale = 0.125f * 1.44269504088896340736f; // (1/sqrt(64)) * log2(e)
    vw[t] = av;
    kw[t] = ak * kscale;
}

// ---------------------------------------------------------------------------
// Kernel B: MFMA flash-attention, spill-free.
//
// Block = 256 threads (4 waves), one (n,h), 512 consecutive px.
// K/V live in LDS as PRE-SPLIT packed bf16 hi/lo MFMA A-fragments (32 KB);
// each wave reads its fragment slices per tile via ds_read_b128 (stride-16B,
// conflict-free). No K/V register residency -> no scratch spills.
//
// Residual comes from the Q registers (no second feature read):
// for C/D reg (u,r): dd = 32u+8(r>>2)+4hi+(r&3); the needed feature value is
// q[s=2u+(r>>3)][i=4hi+(r&3)] of lane-half hs=(r>>2)&1 -> one
// permlane32_swap(q[j], q[4+j]) per (s,j) yields (hs=0, hs=1) for all lanes.
//
// MFMA layouts (32x32x16_bf16):
//   A: row=lane&31, k=8*(lane>>5)+i   B: col=lane&31, k=8*(lane>>5)+i
//   C/D: col=lane&31, row=(r&3)+8*(r>>2)+4*(lane>>5)
// ---------------------------------------------------------------------------
__global__ __launch_bounds__(256, 3) void attn_kernel(
    const float* __restrict__ feature,
    const float* __restrict__ vw, const float* __restrict__ kw,
    float* __restrict__ out)
{
    __shared__ u32x4 ldsK[2][2][4][64];   // [hi/lo][t][s][lane]  16 KB
    __shared__ u32x4 ldsV[2][2][4][64];   // [hi/lo][u][s][lane]  16 KB

    const int tid  = threadIdx.x;
    const int lane = tid & 63;
    const int w    = tid >> 6;       // wave 0..3
    const int c    = lane & 31;
    const int hi   = lane >> 5;

    const int bid = blockIdx.x;      // 2048 = 32 px-groups * 64 (n,h)
    const int nh  = bid & 63;
    const int grp = bid >> 6;        // 512-px group

    const float* Kb = kw + (size_t)nh * (D_H * L_T);   // K[dd][l]
    const float* Vb = vw + (size_t)nh * (D_H * L_T);   // V[dd][l]

    // ---- cooperative staging: waves 0,1 build K-frags (t=w), waves 2,3 V (u=w-2)
    if (w < 2) {
        const int t = w;
#pragma unroll
        for (int s = 0; s < 4; ++s) {
            float tmp[8];
#pragma unroll
            for (int i = 0; i < 8; ++i)
                tmp[i] = Kb[(16 * s + 8 * hi + i) * L_T + 32 * t + c];  // A[l][d] = K[d][l]
            u32x4 h, l;
            split8(tmp, h, l);
            ldsK[0][t][s][lane] = h;
            ldsK[1][t][s][lane] = l;
        }
    } else {
        const int u = w - 2;
#pragma unroll
        for (int s = 0; s < 4; ++s) {
            const float* p = Vb + (size_t)(32 * u + c) * L_T + 16 * s + 8 * hi; // 32B-aligned
            float4 q0 = *(const float4*)(p);
            float4 q1 = *(const float4*)(p + 4);
            float tmp[8] = {q0.x, q0.y, q0.z, q0.w, q1.x, q1.y, q1.z, q1.w};
            u32x4 h, l;
            split8(tmp, h, l);
            ldsV[0][u][s][lane] = h;
            ldsV[1][u][s][lane] = l;
        }
    }
    __syncthreads();

    const size_t fb = (size_t)nh * D_H * HW_PX;

#pragma unroll 1
    for (int it = 0; it < 4; ++it) {
        const int px = grp * 512 + w * 128 + it * 32 + c;

        // ---- QK^T: S^T[l][px]
        f32x16 accS[2];
#pragma unroll
        for (int r = 0; r < 16; ++r) { accS[0][r] = 0.f; accS[1][r] = 0.f; }

        float presA[4][4], presB[4][4];   // residual values, statically indexed

#pragma unroll
        for (int s = 0; s < 4; ++s) {
            float q[8];
#pragma unroll
            for (int i = 0; i < 8; ++i)        // Q[d][px]: 128B-coalesced per half-wave
                q[i] = feature[fb + (size_t)(16 * s + 8 * hi + i) * HW_PX + px];
            u32x4 qh, ql;
            split8(q, qh, ql);
            u32x4 kh0 = ldsK[0][0][s][lane];
            u32x4 kh1 = ldsK[0][1][s][lane];
            u32x4 kl0 = ldsK[1][0][s][lane];
            u32x4 kl1 = ldsK[1][1][s][lane];
            accS[0] = mfma_bf16(kh0, qh, accS[0]);
            accS[0] = mfma_bf16(kh0, ql, accS[0]);
            accS[0] = mfma_bf16(kl0, qh, accS[0]);
            accS[1] = mfma_bf16(kh1, qh, accS[1]);
            accS[1] = mfma_bf16(kh1, ql, accS[1]);
            accS[1] = mfma_bf16(kl1, qh, accS[1]);
            // residual redistribution while q is live
#pragma unroll
            for (int j = 0; j < 4; ++j) {
                auto pr = __builtin_amdgcn_permlane32_swap(
                    __float_as_uint(q[j]), __float_as_uint(q[4 + j]), false, false);
                presA[s][j] = __uint_as_float(pr[0]);   // source half 0
                presB[s][j] = __uint_as_float(pr[1]);   // source half 1
            }
        }

        // ---- softmax over l (base-2 domain; scale folded into kw)
        float m = accS[0][0];
#pragma unroll
        for (int r = 1; r < 16; ++r) m = fmaxf(m, accS[0][r]);
#pragma unroll
        for (int r = 0; r < 16; ++r) m = fmaxf(m, accS[1][r]);
        m = fmaxf(m, __shfl_xor(m, 32));
        float sum = 0.f;
#pragma unroll
        for (int t = 0; t < 2; ++t)
#pragma unroll
            for (int r = 0; r < 16; ++r) {
                float e = __builtin_amdgcn_exp2f(accS[t][r] - m);
                accS[t][r] = e;                 // unnormalized P in-place
                sum += e;
            }
        sum += __shfl_xor(sum, 32);
        const float rinv = 1.0f / sum;

        // ---- PV: O^T[dd][px]
        f32x16 accO[2];
#pragma unroll
        for (int r = 0; r < 16; ++r) { accO[0][r] = 0.f; accO[1][r] = 0.f; }

#pragma unroll
        for (int s = 0; s < 4; ++s) {
            const int t  = s >> 1;
            const int b0 = 8 * (s & 1);
            float e0 = accS[t][b0 + 0], e1 = accS[t][b0 + 1];
            float e2 = accS[t][b0 + 2], e3 = accS[t][b0 + 3];
            float e4 = accS[t][b0 + 4], e5 = accS[t][b0 + 5];
            float e6 = accS[t][b0 + 6], e7 = accS[t][b0 + 7];
            unsigned xh0 = pk_bf16(e0, e1), xh1 = pk_bf16(e2, e3);
            unsigned yh0 = pk_bf16(e4, e5), yh1 = pk_bf16(e6, e7);
            unsigned xl0 = pk_bf16(e0 - lo_f(xh0), e1 - hi_f(xh0));
            unsigned xl1 = pk_bf16(e2 - lo_f(xh1), e3 - hi_f(xh1));
            unsigned yl0 = pk_bf16(e4 - lo_f(yh0), e5 - hi_f(yh0));
            unsigned yl1 = pk_bf16(e6 - lo_f(yh1), e7 - hi_f(yh1));
            auto r0 = __builtin_amdgcn_permlane32_swap(xh0, yh0, false, false);
            auto r1 = __builtin_amdgcn_permlane32_swap(xh1, yh1, false, false);
            auto r2 = __builtin_amdgcn_permlane32_swap(xl0, yl0, false, false);
            auto r3 = __builtin_amdgcn_permlane32_swap(xl1, yl1, false, false);
            u32x4 pbh, pbl;
            pbh[0] = r0[0]; pbh[1] = r1[0]; pbh[2] = r0[1]; pbh[3] = r1[1];
            pbl[0] = r2[0]; pbl[1] = r3[0]; pbl[2] = r2[1]; pbl[3] = r3[1];
            u32x4 vh0 = ldsV[0][0][s][lane];
            u32x4 vh1 = ldsV[0][1][s][lane];
            u32x4 vl0 = ldsV[1][0][s][lane];
            u32x4 vl1 = ldsV[1][1][s][lane];
            accO[0] = mfma_bf16(vh0, pbh, accO[0]);
            accO[0] = mfma_bf16(vh0, pbl, accO[0]);
            accO[0] = mfma_bf16(vl0, pbh, accO[0]);
            accO[1] = mfma_bf16(vh1, pbh, accO[1]);
            accO[1] = mfma_bf16(vh1, pbl, accO[1]);
            accO[1] = mfma_bf16(vl1, pbh, accO[1]);
        }

        // ---- epilogue: normalize + residual(from regs) + store
#pragma unroll
        for (int u = 0; u < 2; ++u)
#pragma unroll
            for (int r = 0; r < 16; ++r) {
                const int dd = 32 * u + (r & 3) + 8 * (r >> 2) + 4 * hi;
                const size_t a = fb + (size_t)dd * HW_PX + px;
                const int sS = 2 * u + (r >> 3);
                const int jj = r & 3;
                float fres = ((r >> 2) & 1) ? presB[sS][jj] : presA[sS][jj];
                out[a] = fmaf(accO[u][r], rinv, fres);
            }
    }
}

// ---------------------------------------------------------------------------
extern "C" void kernel_launch(void* const* d_in, const int* in_sizes, int n_in,
                              void* d_out, int out_size, void* d_ws, size_t ws_size,
                              hipStream_t stream)
{
    const float* feature = (const float*)d_in[0];
    const float* token   = (const float*)d_in[1];
    const float* Wv      = (const float*)d_in[2];
    const float* bv      = (const float*)d_in[3];
    const float* Wk      = (const float*)d_in[4];
    const float* bk      = (const float*)d_in[5];
    float* out = (float*)d_out;

    float* vw = (float*)d_ws;                       // 262144 floats
    float* kw = vw + (size_t)N_B * C_CH * L_T;      // 262144 floats

    proj_kernel<<<(N_B * C_CH * L_T) / 256, 256, 0, stream>>>(token, Wv, bv, Wk, bk, vw, kw);

    // 32 px-groups (512 px each) x 64 (n,h), 4 waves per block
    attn_kernel<<<32 * 64, 256, 0, stream>>>(feature, vw, kw, out);
}